// Round 3
// baseline (181.106 us; speedup 1.0000x reference)
//
#include <hip/hip_runtime.h>
#include <hip/hip_bf16.h>

// FlowNetC correlation via bf16 MFMA, fp32 accumulate.
// out[b, r*21+dx, y, x] = (1/256) * sum_c in1[b,c,y,x] * in2[b,c, y+2r-20, x+2dx-20]
//
// Round-7 structure:
//  1) conv_in2: in2 fp32 -> in2t bf16 frag-native chunks [b][y][c8][x][c%8].
//     512-thread blocks, float4 loads (8 in flight/thread), coalesced uint4
//     stores. One 16-B chunk = one MFMA B-fragment slice.
//  2) corr_mfma: block = (b, y-pair {y0,y0+2}), 16 waves, 1 block/CU.
//     Wave w: tile (m = w&3, n = m + (w>>2)). A-frags for both y's in VGPRs.
//     B-frags prefetched into registers ONE ITER AHEAD, direct from L2
//     (b = blk&7 pins batch to one XCD L2). KEY CHANGE vs round-5/6: the
//     per-iter barrier is a RAW s_barrier preceded by lgkmcnt(0) ONLY --
//     no vmcnt(0) drain. The barrier protects slds (LDS-only dep); global
//     stores are fire-and-forget and retire across iterations. Round-5/6
//     drained ~10.7KB of stores per iter inside the barrier (~2700 cy/iter
//     serial at measured 0.96 TB/s write rate) -> MfmaUtil 12%, 6.6K cy/iter.

typedef short    bf16x8 __attribute__((ext_vector_type(8)));
typedef float    f32x4  __attribute__((ext_vector_type(4)));

constexpr int CSTRIDE = 64 * 64;        // fp32 channel plane
constexpr int BSTRIDE = 256 * CSTRIDE;  // fp32 batch

union BF2 { __hip_bfloat162 h; unsigned u; };

__device__ inline unsigned pack_bf2(float lo, float hi) {
    BF2 cv;
    cv.h = __float22bfloat162_rn(make_float2(lo, hi));
    return cv.u;
}

#define ELT(v4, xi) ((xi) == 0 ? (v4).x : (xi) == 1 ? (v4).y : (xi) == 2 ? (v4).z : (v4).w)

// ---------------- prepass: in2 -> bf16 frag-native chunks ----------------
__global__ __launch_bounds__(512)
void conv_in2(const float* __restrict__ in2, uint4* __restrict__ out16)
{
    const int tid = threadIdx.x;
    const int b = blockIdx.x & 7;
    const int y = blockIdx.x >> 3;
    const int c8 = tid >> 4;              // 0..31
    const int x0 = (tid & 15) * 4;        // 4 consecutive x per thread
    const float* p = in2 + b * BSTRIDE + y * 64 + c8 * 8 * CSTRIDE + x0;
    uint4* dst = out16 + (b * 64 + y) * 2048 + c8 * 64 + x0;

    float4 v[8];
#pragma unroll
    for (int j = 0; j < 8; ++j)
        v[j] = *reinterpret_cast<const float4*>(p + j * CSTRIDE);
#pragma unroll
    for (int xi = 0; xi < 4; ++xi) {
        uint4 o;
        o.x = pack_bf2(ELT(v[0], xi), ELT(v[1], xi));
        o.y = pack_bf2(ELT(v[2], xi), ELT(v[3], xi));
        o.z = pack_bf2(ELT(v[4], xi), ELT(v[5], xi));
        o.w = pack_bf2(ELT(v[6], xi), ELT(v[7], xi));
        dst[xi] = o;
    }
}

// ---------------- main correlation kernel ----------------
__global__ __launch_bounds__(1024, 4)
void corr_mfma(const float* __restrict__ in1,
               const uint4* __restrict__ in2t,
               float* __restrict__ out)
{
    __shared__ float slds[2][2][21 * 65];   // [iter&1][y-half], 21.8 KB

    const int tid  = threadIdx.x;
    const int lane = tid & 63;
    const int w    = tid >> 6;          // wave 0..15
    const int cl   = lane & 15;         // MFMA m/n lane index
    const int q    = lane >> 4;         // MFMA quad
    const int m    = w & 3;             // M-tile: gx in [16m, 16m+16)
    const int n    = m + (w >> 2);      // N-tile: col in [16n, 16n+16), n in 0..6
    const int b    = blockIdx.x & 7;    // batch -> XCD affinity
    const int p    = blockIdx.x >> 3;   // 0..31
    const int y0   = 4 * (p >> 1) + (p & 1);   // pair (y0, y0+2), covers all y

    // ---- A fragments for both y's: af[h][k] = in1[b, 32k+8q+j, y0+2h, 16m+cl] ----
    bf16x8 af[2][8];
#pragma unroll
    for (int h = 0; h < 2; ++h) {
        const float* pb = in1 + b * BSTRIDE + (y0 + 2 * h) * 64 + 16 * m + cl
                        + 8 * q * CSTRIDE;
#pragma unroll
        for (int k = 0; k < 8; ++k) {
            const float* pp = pb + 32 * k * CSTRIDE;
            float v[8];
#pragma unroll
            for (int j = 0; j < 8; ++j) v[j] = pp[j * CSTRIDE];
#pragma unroll
            for (int j = 0; j < 4; ++j)
                ((unsigned*)&af[h][k])[j] = pack_bf2(v[2 * j], v[2 * j + 1]);
        }
    }

    const int  x    = 16 * n + cl - 20;              // W col -> in2 x (may be OOB)
    const bool xok  = (x >= 0) && (x < 64);
    const int  gcol = 16 * n + cl;

    // ---- B register buffer (one in2t row slice per iter, prefetched 1 ahead) ----
    uint4 breg[8];
#pragma unroll
    for (int k = 0; k < 8; ++k) breg[k] = uint4{0u, 0u, 0u, 0u};   // OOB-x lanes stay 0

    // prologue: prefetch row for iter 0 (valid iff y0 >= 20)
    {
        const int yy0 = y0 - 20;
        if (yy0 >= 0 && xok) {
            const uint4* src = in2t + (b * 64 + yy0) * 2048 + q * 64 + x;
#pragma unroll
            for (int k = 0; k < 8; ++k) breg[k] = src[k * 256];
        }
    }

    for (int i = 0; i < 22; ++i) {
        const int  ib      = i & 1;
        const int  yy      = y0 - 20 + 2 * i;
        const bool compute = (yy >= 0) && (yy < 64);   // block-uniform

        f32x4 acc0 = {0.f, 0.f, 0.f, 0.f};
        f32x4 acc1 = {0.f, 0.f, 0.f, 0.f};
        if (compute) {
#pragma unroll
            for (int k = 0; k < 8; ++k) {
                const bf16x8 bf = __builtin_bit_cast(bf16x8, breg[k]);
                acc0 = __builtin_amdgcn_mfma_f32_16x16x32_bf16(af[0][k], bf, acc0, 0, 0, 0);
                acc1 = __builtin_amdgcn_mfma_f32_16x16x32_bf16(af[1][k], bf, acc1, 0, 0, 0);
            }
        }

        // prefetch next row into breg (WAR on MFMA reads keeps order safe);
        // issued BEFORE this iter's stores so the next MFMA wait is a counted
        // vmcnt that does NOT force store retire.
        {
            const int yn = yy + 2;
            if ((i + 1) < 22 && yn >= 0 && yn < 64 && xok) {
                const uint4* src = in2t + (b * 64 + yn) * 2048 + q * 64 + x;
#pragma unroll
                for (int k = 0; k < 8; ++k) breg[k] = src[k * 256];
            }
        }

        if (compute) {
            // diagonal gather: D[row=4q+i4][col=cl]; gx = 16m+4q+i4, d2 = gcol-gx
#pragma unroll
            for (int i4 = 0; i4 < 4; ++i4) {
                const int gx = 16 * m + 4 * q + i4;
                const int d2 = gcol - gx;
                if (d2 >= 0 && d2 <= 40 && !(d2 & 1)) {
                    slds[ib][0][(d2 >> 1) * 65 + gx] = acc0[i4];
                    slds[ib][1][(d2 >> 1) * 65 + gx] = acc1[i4];
                }
            }
            // LDS-only fence: NO vmcnt drain (stores stay in flight)
            __builtin_amdgcn_sched_barrier(0);
            asm volatile("s_waitcnt lgkmcnt(0)" ::: "memory");
            __builtin_amdgcn_s_barrier();
            __builtin_amdgcn_sched_barrier(0);
        }

        // epilogue: half0 -> (y0, r=i), half1 -> (y0+2, r=i-1); coalesced,
        // fire-and-forget (never drained inside the loop)
        const int r0 = i, r1 = i - 1;
#pragma unroll
        for (int t3 = 0; t3 < 3; ++t3) {
            const int t = tid + 1024 * t3;
            if (t < 2 * 21 * 64) {
                const int h  = (t >= 1344) ? 1 : 0;
                const int u  = t - 1344 * h;
                const int dx = u >> 6, gx = u & 63;
                const int r  = h ? r1 : r0;
                if (r >= 0 && r <= 20) {
                    const float val = compute ? slds[ib][h][dx * 65 + gx] * (1.f / 256.f)
                                              : 0.f;
                    out[((b * 441 + r * 21 + dx) * 64 + y0 + 2 * h) * 64 + gx] = val;
                }
            }
        }
        // slds[ib] reuse at iter i+2 is fenced by the lgkmcnt(0)+barrier inside
        // iter i+1 (waits this iter's epilogue ds_reads; T-run is contiguous).
    }
}

extern "C" void kernel_launch(void* const* d_in, const int* in_sizes, int n_in,
                              void* d_out, int out_size, void* d_ws, size_t ws_size,
                              hipStream_t stream) {
    const float* in1 = (const float*)d_in[0];
    const float* in2 = (const float*)d_in[1];
    float* out = (float*)d_out;

    conv_in2<<<dim3(512), dim3(512), 0, stream>>>(in2, (uint4*)d_ws);
    corr_mfma<<<dim3(256), dim3(1024), 0, stream>>>(in1, (const uint4*)d_ws, out);
}

// Round 4
// 161.709 us; speedup vs baseline: 1.1199x; 1.1199x over previous
//
#include <hip/hip_runtime.h>
#include <hip/hip_bf16.h>

// FlowNetC correlation via bf16 MFMA, fp32 accumulate.
// out[b, r*21+dx, y, x] = (1/256) * sum_c in1[b,c,y,x] * in2[b,c, y+2r-20, x+2dx-20]
//
// Round-8 structure:
//  1) conv_in2: in2 fp32 -> in2t bf16 frag-native chunks [b][y][c8][x][c%8]
//     (float4 loads, coalesced uint4 stores). One 16-B chunk = one B-frag slice.
//  2) corr_mfma: block = (b, y-pair {y0,y0+2}), 16 waves, 1 block/CU.
//     B path: in2t row (32 KB) staged ONCE per block into LDS via
//     global_load_lds (zero VGPR cost), TRIPLE-buffered and issued TWO
//     iterations ahead, right AFTER __syncthreads. The stage is only forced
//     to retire by the vmcnt(0) inside the NEXT iteration's __syncthreads --
//     a full compute-phase of age -- so the drain is free. This fixes:
//       r5 (60.5us): 16 waves x 8KB direct L2 loads in lockstep -> 128KB/CU-iter
//                    L1-miss storm, ~exposed L2 latency every iter.
//       r6 (66.4us): LDS staging but issued SAME-iter -> vmcnt(0) exposed
//                    the full stage latency.
//       r7 (83.4us): register prefetch blew the 128-reg cap of a 1024-thr
//                    block -> per-iter scratch spill (FETCH +24MB, WRITE +43MB).
//     Compute reads B via conflict-free contiguous ds_read_b128 (1KB/wave).
//     Epilogue unchanged from r5: slds[i&1] diagonal gather -> coalesced stores.

typedef short    bf16x8 __attribute__((ext_vector_type(8)));
typedef float    f32x4  __attribute__((ext_vector_type(4)));

constexpr int CSTRIDE = 64 * 64;        // fp32 channel plane
constexpr int BSTRIDE = 256 * CSTRIDE;  // fp32 batch

union BF2 { __hip_bfloat162 h; unsigned u; };

__device__ inline unsigned pack_bf2(float lo, float hi) {
    BF2 cv;
    cv.h = __float22bfloat162_rn(make_float2(lo, hi));
    return cv.u;
}

#define ELT(v4, xi) ((xi) == 0 ? (v4).x : (xi) == 1 ? (v4).y : (xi) == 2 ? (v4).z : (v4).w)

// ---------------- prepass: in2 -> bf16 frag-native chunks ----------------
__global__ __launch_bounds__(512)
void conv_in2(const float* __restrict__ in2, uint4* __restrict__ out16)
{
    const int tid = threadIdx.x;
    const int b = blockIdx.x & 7;
    const int y = blockIdx.x >> 3;
    const int c8 = tid >> 4;              // 0..31
    const int x0 = (tid & 15) * 4;        // 4 consecutive x per thread
    const float* p = in2 + b * BSTRIDE + y * 64 + c8 * 8 * CSTRIDE + x0;
    uint4* dst = out16 + (b * 64 + y) * 2048 + c8 * 64 + x0;

    float4 v[8];
#pragma unroll
    for (int j = 0; j < 8; ++j)
        v[j] = *reinterpret_cast<const float4*>(p + j * CSTRIDE);
#pragma unroll
    for (int xi = 0; xi < 4; ++xi) {
        uint4 o;
        o.x = pack_bf2(ELT(v[0], xi), ELT(v[1], xi));
        o.y = pack_bf2(ELT(v[2], xi), ELT(v[3], xi));
        o.z = pack_bf2(ELT(v[4], xi), ELT(v[5], xi));
        o.w = pack_bf2(ELT(v[6], xi), ELT(v[7], xi));
        dst[xi] = o;
    }
}

// ---------------- main correlation kernel ----------------
__device__ inline void stage64(const uint4* __restrict__ gsrc, uint4* lds_dst) {
    // one instr: 64 lanes x 16B, global per-lane src -> LDS wave-uniform base + lane*16
    __builtin_amdgcn_global_load_lds(
        (const __attribute__((address_space(1))) void*)gsrc,
        (__attribute__((address_space(3))) void*)lds_dst,
        16, 0, 0);
}

__global__ __launch_bounds__(1024, 4)
void corr_mfma(const float* __restrict__ in1,
               const uint4* __restrict__ in2t,
               float* __restrict__ out)
{
    __shared__ __align__(16) uint4 rowbuf[3][2048];   // 96 KB: in2t row triple-buffer
    __shared__ float slds[2][2][21 * 65];             // 21.8 KB epilogue dbuf
    __shared__ __align__(16) uint4 zchunk;            // zero B-frag for OOB x

    const int tid  = threadIdx.x;
    const int lane = tid & 63;
    const int w    = tid >> 6;          // wave 0..15
    const int cl   = lane & 15;         // MFMA m/n lane index
    const int q    = lane >> 4;         // MFMA quad
    const int m    = w & 3;             // M-tile: gx in [16m, 16m+16)
    const int n    = m + (w >> 2);      // N-tile: col in [16n, 16n+16), n in 0..6
    const int b    = blockIdx.x & 7;    // batch -> XCD affinity
    const int p    = blockIdx.x >> 3;   // 0..31
    const int y0   = 4 * (p >> 1) + (p & 1);   // pair (y0, y0+2), covers all y

    if (tid == 0) { uint4 z = {0u, 0u, 0u, 0u}; zchunk = z; }

    // ---- A fragments for both y's: af[h][k] = in1[b, 32k+8q+j, y0+2h, 16m+cl] ----
    bf16x8 af[2][8];
#pragma unroll
    for (int h = 0; h < 2; ++h) {
        const float* pb = in1 + b * BSTRIDE + (y0 + 2 * h) * 64 + 16 * m + cl
                        + 8 * q * CSTRIDE;
#pragma unroll
        for (int k = 0; k < 8; ++k) {
            const float* pp = pb + 32 * k * CSTRIDE;
            float v[8];
#pragma unroll
            for (int j = 0; j < 8; ++j) v[j] = pp[j * CSTRIDE];
#pragma unroll
            for (int j = 0; j < 4; ++j)
                ((unsigned*)&af[h][k])[j] = pack_bf2(v[2 * j], v[2 * j + 1]);
        }
    }

    const int  x    = 16 * n + cl - 20;              // W col -> in2 x (may be OOB)
    const bool xok  = (x >= 0) && (x < 64);
    const int  gcol = 16 * n + cl;
    const int  c0   = w * 128 + lane;                // this wave's staging slice

    // ---- prologue: stage rows for iters 0 and 1 ----
    {
        const int yA = y0 - 20;                      // iter-0 row
        if (yA >= 0 && yA < 64) {
            const uint4* rp = in2t + (b * 64 + yA) * 2048;
            stage64(rp + c0,      &rowbuf[0][w * 128]);
            stage64(rp + c0 + 64, &rowbuf[0][w * 128 + 64]);
        }
        const int yB = y0 - 18;                      // iter-1 row
        if (yB >= 0 && yB < 64) {
            const uint4* rp = in2t + (b * 64 + yB) * 2048;
            stage64(rp + c0,      &rowbuf[1][w * 128]);
            stage64(rp + c0 + 64, &rowbuf[1][w * 128 + 64]);
        }
    }
    __syncthreads();   // drains prologue stages (vmcnt(0)) + zchunk write

    int cur = 0;       // rowbuf index for this iter (= i % 3)

    for (int i = 0; i < 22; ++i) {
        const int  ib      = i & 1;
        const int  yy      = y0 - 20 + 2 * i;
        const bool compute = (yy >= 0) && (yy < 64);   // block-uniform

        if (compute) {
            f32x4 acc0 = {0.f, 0.f, 0.f, 0.f};
            f32x4 acc1 = {0.f, 0.f, 0.f, 0.f};
            const uint4* rbase = &rowbuf[cur][q * 64 + x];
#pragma unroll
            for (int k = 0; k < 8; ++k) {
                const uint4* pk = xok ? (rbase + k * 256) : &zchunk;
                const bf16x8 bf = __builtin_bit_cast(bf16x8, *pk);
                acc0 = __builtin_amdgcn_mfma_f32_16x16x32_bf16(af[0][k], bf, acc0, 0, 0, 0);
                acc1 = __builtin_amdgcn_mfma_f32_16x16x32_bf16(af[1][k], bf, acc1, 0, 0, 0);
            }
            // diagonal gather: D[row=4q+i4][col=cl]; gx = 16m+4q+i4, d2 = gcol-gx
#pragma unroll
            for (int i4 = 0; i4 < 4; ++i4) {
                const int gx = 16 * m + 4 * q + i4;
                const int d2 = gcol - gx;
                if (d2 >= 0 && d2 <= 40 && !(d2 & 1)) {
                    slds[ib][0][(d2 >> 1) * 65 + gx] = acc0[i4];
                    slds[ib][1][(d2 >> 1) * 65 + gx] = acc1[i4];
                }
            }
        }
        __syncthreads();
        // The vmcnt(0)+lgkmcnt(0) inside this barrier is ~free: the newest
        // outstanding vm ops (stage(i+1), stores of iter i-1) were issued a
        // full compute-phase ago.

        // ---- post-barrier: stage row for iter i+2 into rowbuf[(cur+2)%3].
        // That buffer's last readers (iter i-1) finished before barrier(i-1);
        // its data is consumed only after barrier(i+1) forces this stage. ----
        {
            const int yn2 = yy + 4;                   // row for iter i+2
            if (i < 20 && yn2 >= 0 && yn2 < 64) {
                int nb = cur + 2; if (nb >= 3) nb -= 3;
                const uint4* rp = in2t + (b * 64 + yn2) * 2048;
                stage64(rp + c0,      &rowbuf[nb][w * 128]);
                stage64(rp + c0 + 64, &rowbuf[nb][w * 128 + 64]);
            }
        }

        // ---- epilogue: half0 -> (y0, r=i), half1 -> (y0+2, r=i-1) ----
        const int r0 = i, r1 = i - 1;
#pragma unroll
        for (int t3 = 0; t3 < 3; ++t3) {
            const int t = tid + 1024 * t3;
            if (t < 2 * 21 * 64) {
                const int h  = (t >= 1344) ? 1 : 0;
                const int u  = t - 1344 * h;
                const int dx = u >> 6, gx = u & 63;
                const int r  = h ? r1 : r0;
                if (r >= 0 && r <= 20) {
                    const float val = compute ? slds[ib][h][dx * 65 + gx] * (1.f / 256.f)
                                              : 0.f;
                    out[((b * 441 + r * 21 + dx) * 64 + y0 + 2 * h) * 64 + gx] = val;
                }
            }
        }
        // slds[ib] reuse at iter i+2 is fenced by barrier(i+1).

        ++cur; if (cur >= 3) cur = 0;
    }
}

extern "C" void kernel_launch(void* const* d_in, const int* in_sizes, int n_in,
                              void* d_out, int out_size, void* d_ws, size_t ws_size,
                              hipStream_t stream) {
    const float* in1 = (const float*)d_in[0];
    const float* in2 = (const float*)d_in[1];
    float* out = (float*)d_out;

    conv_in2<<<dim3(512), dim3(512), 0, stream>>>(in2, (uint4*)d_ws);
    corr_mfma<<<dim3(256), dim3(1024), 0, stream>>>(in1, (const uint4*)d_ws, out);
}

// Round 5
// 157.358 us; speedup vs baseline: 1.1509x; 1.0277x over previous
//
#include <hip/hip_runtime.h>
#include <hip/hip_bf16.h>

// FlowNetC correlation via bf16 MFMA, fp32 accumulate.
// out[b, r*21+dx, y, x] = (1/256) * sum_c in1[b,c,y,x] * in2[b,c, y+2r-20, x+2dx-20]
//
// Round-9 structure: BARRIER-FREE wave-autonomous kernel.
//   Evidence: r5 (direct L2 B-loads) 60.5us, r6 (LDS stage 1-ahead) 66.4,
//   r8 (LDS stage 2-ahead) 67.2 -- all ~6.6-7.3K cy/iter, B-path irrelevant;
//   all pipes <21% busy, occupancy 30% => latency-bound on the per-iter
//   block-wide barrier (16-wave lockstep, 1 block/CU, nothing to overlap).
//   The barrier only existed for the slds diagonal transpose. But ownership
//   is wave-local: output (d2=2dx, gx) belongs to exactly one wave
//   (m=gx>>4, n=(gx+d2)>>4, d=n-m in 0..3) and one (cl,q,i4) element in it.
//   So each wave scatters to a PRIVATE slds patch and reads it back itself:
//   same-wave LDS ordering (compiler lgkmcnt) -- NO __syncthreads anywhere.
//   16 waves free-run per CU and mutually hide L2/LDS/store latency.
//   Stores: per (d2) a contiguous <=16-lane 64B segment; band-edge partial
//   lines are completed by the neighbor tile's wave and merge in L2.

typedef short    bf16x8 __attribute__((ext_vector_type(8)));
typedef float    f32x4  __attribute__((ext_vector_type(4)));

constexpr int CSTRIDE = 64 * 64;        // fp32 channel plane
constexpr int BSTRIDE = 256 * CSTRIDE;  // fp32 batch

union BF2 { __hip_bfloat162 h; unsigned u; };

__device__ inline unsigned pack_bf2(float lo, float hi) {
    BF2 cv;
    cv.h = __float22bfloat162_rn(make_float2(lo, hi));
    return cv.u;
}

#define ELT(v4, xi) ((xi) == 0 ? (v4).x : (xi) == 1 ? (v4).y : (xi) == 2 ? (v4).z : (v4).w)

__device__ __align__(16) const uint4 ZERO16 = {0u, 0u, 0u, 0u};

// ---------------- prepass: in2 -> bf16 frag-native chunks ----------------
__global__ __launch_bounds__(512)
void conv_in2(const float* __restrict__ in2, uint4* __restrict__ out16)
{
    const int tid = threadIdx.x;
    const int b = blockIdx.x & 7;
    const int y = blockIdx.x >> 3;
    const int c8 = tid >> 4;              // 0..31
    const int x0 = (tid & 15) * 4;        // 4 consecutive x per thread
    const float* p = in2 + b * BSTRIDE + y * 64 + c8 * 8 * CSTRIDE + x0;
    uint4* dst = out16 + (b * 64 + y) * 2048 + c8 * 64 + x0;

    float4 v[8];
#pragma unroll
    for (int j = 0; j < 8; ++j)
        v[j] = *reinterpret_cast<const float4*>(p + j * CSTRIDE);
#pragma unroll
    for (int xi = 0; xi < 4; ++xi) {
        uint4 o;
        o.x = pack_bf2(ELT(v[0], xi), ELT(v[1], xi));
        o.y = pack_bf2(ELT(v[2], xi), ELT(v[3], xi));
        o.z = pack_bf2(ELT(v[4], xi), ELT(v[5], xi));
        o.w = pack_bf2(ELT(v[6], xi), ELT(v[7], xi));
        dst[xi] = o;
    }
}

// ---------------- main correlation kernel (no barriers) ----------------
__global__ __launch_bounds__(1024, 4)
void corr_mfma(const float* __restrict__ in1,
               const uint4* __restrict__ in2t,
               float* __restrict__ out)
{
    // per-wave private scratch: [wave][half][d2/2][gx_local(padded)]
    __shared__ float slds[16][2][21][17];   // 45.7 KB

    const int tid  = threadIdx.x;
    const int lane = tid & 63;
    const int w    = tid >> 6;          // wave 0..15
    const int cl   = lane & 15;         // MFMA m/n lane index
    const int q    = lane >> 4;         // MFMA quad
    const int m    = w & 3;             // M-tile: gx in [16m, 16m+16)
    const int d    = w >> 2;            // band offset 0..3
    const int n    = m + d;             // N-tile: col in [16n, 16n+16)
    const int b    = blockIdx.x & 7;    // batch -> XCD affinity
    const int p    = blockIdx.x >> 3;   // 0..31
    const int y0   = 4 * (p >> 1) + (p & 1);   // pair (y0, y0+2), covers all y

    // ---- A fragments for both y's: af[h][k] = in1[b, 32k+8q+j, y0+2h, 16m+cl] ----
    bf16x8 af[2][8];
#pragma unroll
    for (int h = 0; h < 2; ++h) {
        const float* pb = in1 + b * BSTRIDE + (y0 + 2 * h) * 64 + 16 * m + cl
                        + 8 * q * CSTRIDE;
#pragma unroll
        for (int k = 0; k < 8; ++k) {
            const float* pp = pb + 32 * k * CSTRIDE;
            float v[8];
#pragma unroll
            for (int j = 0; j < 8; ++j) v[j] = pp[j * CSTRIDE];
#pragma unroll
            for (int j = 0; j < 4; ++j)
                ((unsigned*)&af[h][k])[j] = pack_bf2(v[2 * j], v[2 * j + 1]);
        }
    }

    const int  x   = 16 * n + cl - 20;               // in2 x (may be OOB)
    const bool xok = (x >= 0) && (x < 64);

    // band d2-range of this wave (even values): [lo_e, hi_e]
    const int lo_e = (d == 0) ? 0 : 16 * d - 14;       // 0, 2, 18, 34
    const int hi_e = (16 * d + 14 > 40) ? 40 : 16 * d + 14;   // 14, 30, 40, 40
    const int cnt    = ((hi_e - lo_e) >> 1) + 1;       // 8, 15, 12, 4
    const int rounds = (cnt + 3) >> 2;                 // 2, 4, 3, 1

    float* ms = &slds[w][0][0][0];      // [h*357 + (d2>>1)*17 + gxl]

    const int s   = lane >> 4;          // segment slot 0..3 in store rounds
    const int pos = lane & 15;          // gx_local in store rounds

    for (int i = 0; i < 22; ++i) {
        const int  yy      = y0 - 20 + 2 * i;
        const bool compute = (yy >= 0) && (yy < 64);
        const bool h0v     = (i <= 20);                // half0 r = i valid
        const bool h1v     = (i >= 1);                 // half1 r = i-1 valid

        if (compute) {
            f32x4 acc0 = {0.f, 0.f, 0.f, 0.f};
            f32x4 acc1 = {0.f, 0.f, 0.f, 0.f};
            const uint4* src = in2t + (b * 64 + yy) * 2048 + x;   // + (4k+q)*64
            // two 4-load batches keep <=16 B-regs in flight (af must stay resident)
#pragma unroll
            for (int kb = 0; kb < 2; ++kb) {
                uint4 wv[4];
#pragma unroll
                for (int k4 = 0; k4 < 4; ++k4) {
                    const int k = kb * 4 + k4;
                    const uint4* pk = xok ? (src + (4 * k + q) * 64) : &ZERO16;
                    wv[k4] = *pk;
                }
#pragma unroll
                for (int k4 = 0; k4 < 4; ++k4) {
                    const int k = kb * 4 + k4;
                    const bf16x8 bf = __builtin_bit_cast(bf16x8, wv[k4]);
                    if (h0v) acc0 = __builtin_amdgcn_mfma_f32_16x16x32_bf16(af[0][k], bf, acc0, 0, 0, 0);
                    if (h1v) acc1 = __builtin_amdgcn_mfma_f32_16x16x32_bf16(af[1][k], bf, acc1, 0, 0, 0);
                }
            }
            // wave-local diagonal scatter: elem (cl,q,i4) -> (d2, gxl=4q+i4)
#pragma unroll
            for (int i4 = 0; i4 < 4; ++i4) {
                const int gxl = 4 * q + i4;
                const int d2  = 16 * d + cl - gxl;
                if (d2 >= 0 && d2 <= 40 && !(d2 & 1)) {
                    const int off = (d2 >> 1) * 17 + gxl;
                    if (h0v) ms[off]       = acc0[i4];
                    if (h1v) ms[357 + off] = acc1[i4];
                }
            }
        }

        // wave-local read-back + segment stores (compiler inserts lgkmcnt for
        // the ds_write -> ds_read dependency; same wave => no barrier needed)
        for (int rd = 0; rd < rounds; ++rd) {
            const int d2 = lo_e + 2 * (rd * 4 + s);
            const int al = (16 * d > d2) ? (16 * d - d2) : 0;
            int bl = 16 * d + 16 - d2; if (bl > 16) bl = 16;
            const bool act = (d2 <= hi_e) && (pos >= al) && (pos < bl);
            if (act) {
                const int off = (d2 >> 1) * 17 + pos;
                const int gx  = 16 * m + pos;
                if (h0v) {
                    const float v = compute ? ms[off] * (1.f / 256.f) : 0.f;
                    out[((b * 441 + i * 21 + (d2 >> 1)) * 64 + y0) * 64 + gx] = v;
                }
                if (h1v) {
                    const float v = compute ? ms[357 + off] * (1.f / 256.f) : 0.f;
                    out[((b * 441 + (i - 1) * 21 + (d2 >> 1)) * 64 + (y0 + 2)) * 64 + gx] = v;
                }
            }
        }
    }
}

extern "C" void kernel_launch(void* const* d_in, const int* in_sizes, int n_in,
                              void* d_out, int out_size, void* d_ws, size_t ws_size,
                              hipStream_t stream) {
    const float* in1 = (const float*)d_in[0];
    const float* in2 = (const float*)d_in[1];
    float* out = (float*)d_out;

    conv_in2<<<dim3(512), dim3(512), 0, stream>>>(in2, (uint4*)d_ws);
    corr_mfma<<<dim3(256), dim3(1024), 0, stream>>>(in1, (const uint4*)d_ws, out);
}